// Round 13
// baseline (82.683 us; speedup 1.0000x reference)
//
#include <hip/hip_runtime.h>
#include <hip/hip_bf16.h>
#include <math.h>

#define N 8192
#define D 64
// fold (1/sqrt(D)) * log2(e) into Q so S2 = Qs·K is in base-2 units
#define QSCALE 0.18033688011112042f
#define REP 3

typedef __attribute__((ext_vector_type(8))) short short8;
typedef __attribute__((ext_vector_type(16))) float f32x16;
typedef __attribute__((ext_vector_type(4))) unsigned int ui4;

__device__ inline short f32_to_bf16_bits(float x) {
    unsigned u = __builtin_bit_cast(unsigned, x);
    u += 0x7FFFu + ((u >> 16) & 1u);   // RNE
    return (short)(u >> 16);
}
__device__ inline float bfbits_to_f32(unsigned short u) {
    return __builtin_bit_cast(float, ((unsigned)u) << 16);
}
// v_cvt_pk_bf16_f32: packs two f32 -> two bf16 (RNE) in one VALU op.
__device__ inline unsigned cvt_pk_bf16(float a, float b) {
    unsigned r;
    asm("v_cvt_pk_bf16_f32 %0, %1, %2" : "=v"(r) : "v"(a), "v"(b));
    return r;
}
__device__ inline float max3f(float a, float b, float c) {
    float d;
    asm("v_max3_f32 %0, %1, %2, %3" : "=v"(d) : "v"(a), "v"(b), "v"(c));
    return d;
}

// ---- fused prepass (identical to r12) ----
__global__ __launch_bounds__(256) void fa_conv(const float* __restrict__ q,
                                               const float* __restrict__ k,
                                               const float* __restrict__ v,
                                               short* __restrict__ Qb,
                                               short* __restrict__ Kp,
                                               short* __restrict__ Vp) {
    int bid = blockIdx.x, tid = threadIdx.x;
    if (bid < 512) {
        int i = (bid * 256 + tid) * 4;
        float4 a = *(const float4*)(q + i);
        unsigned lo = cvt_pk_bf16(a.x * QSCALE, a.y * QSCALE);
        unsigned hi = cvt_pk_bf16(a.z * QSCALE, a.w * QSCALE);
        unsigned long long u = (unsigned long long)lo | ((unsigned long long)hi << 32);
        *(unsigned long long*)(Qb + i) = u;
    } else if (bid < 768) {
        int t = bid - 512;
        int c = tid >> 6, l = tid & 63, ql = l & 31, hi = l >> 5;
        const float* src = k + (size_t)(t * 32 + ql) * D + c * 16 + hi * 8;
        float4 a = *(const float4*)(src);
        float4 b = *(const float4*)(src + 4);
        uint4 u = { cvt_pk_bf16(a.x, a.y), cvt_pk_bf16(a.z, a.w),
                    cvt_pk_bf16(b.x, b.y), cvt_pk_bf16(b.z, b.w) };
        *(uint4*)(Kp + (size_t)t * 2048 + c * 512 + l * 8) = u;
    } else {
        int t = bid - 768;
        int dt = tid >> 7, h = (tid >> 6) & 1, hi = (tid >> 5) & 1, ql = tid & 31;
        // kappa-reordered: slot j holds V[key t*32 + h*16 + 4*hi + (j&3) + 8*(j>>2)]
        const float* src = v + (size_t)(t * 32 + h * 16 + hi * 4) * D + dt * 32 + ql;
        float f[8];
#pragma unroll
        for (int j = 0; j < 8; ++j)
            f[j] = src[(size_t)((j & 3) + 8 * (j >> 2)) * D];
        uint4 u = { cvt_pk_bf16(f[0], f[1]), cvt_pk_bf16(f[2], f[3]),
                    cvt_pk_bf16(f[4], f[5]), cvt_pk_bf16(f[6], f[7]) };
        *(uint4*)(Vp + (size_t)t * 2048 + dt * 1024 + h * 512 + hi * 256 + ql * 8) = u;
    }
}

// ---- main: r12 structure, K-loop repeated REP x for direct timing ----
// acc/lsum scale by 1/REP at the end -> outputs identical to 1-pass.
__global__ __launch_bounds__(256) void fa_part_kernel(const short* __restrict__ Qb,
                                                      const short* __restrict__ Kp,
                                                      const short* __restrict__ Vp,
                                                      short* __restrict__ OTb,
                                                      float* __restrict__ Ml,
                                                      int KN) {
    const int qt = blockIdx.x & 63;
    const int s  = blockIdx.x >> 6;
    const int w = threadIdx.x >> 6, lane = threadIdx.x & 63;
    const int ql = lane & 31, hi = lane >> 5;
    const int qrow = qt * 128 + w * 32 + ql;

    const short* qp = Qb + (size_t)qrow * D + hi * 8;
    short8 qf0 = *(const short8*)(qp);
    short8 qf1 = *(const short8*)(qp + 16);
    short8 qf2 = *(const short8*)(qp + 32);
    short8 qf3 = *(const short8*)(qp + 48);

    f32x16 acc0 = {}, acc1 = {};
    float mex = -INFINITY, lsum = 0.f;

    const int t0 = (s * KN) >> 5, nt = KN >> 5;   // 32-key tiles
    const short* kp0 = Kp + (size_t)t0 * 2048 + lane * 8;
    const short* vp0 = Vp + (size_t)t0 * 2048 + lane * 8;

    short8 kA0, kA1, kA2, kA3, kB0, kB1, kB2, kB3;
    short8 vf0, vf1, vf2, vf3;

#define LOADK(d0, d1, d2, d3) do {                                         \
        d0 = *(const short8*)(kp);                                         \
        d1 = *(const short8*)(kp + 512);                                   \
        d2 = *(const short8*)(kp + 1024);                                  \
        d3 = *(const short8*)(kp + 1536);                                  \
        kp += 2048;                                                        \
    } while (0)
#define LOADV() do {                                                       \
        vf0 = *(const short8*)(vp);                                        \
        vf1 = *(const short8*)(vp + 512);                                  \
        vf2 = *(const short8*)(vp + 1024);                                 \
        vf3 = *(const short8*)(vp + 1536);                                 \
        vp += 2048;                                                        \
    } while (0)

#define TILE(K0, K1, K2, K3) do {                                           \
        __builtin_amdgcn_s_setprio(1);                                      \
        f32x16 st = {};                                                     \
        st = __builtin_amdgcn_mfma_f32_32x32x16_bf16(K0, qf0, st, 0, 0, 0); \
        st = __builtin_amdgcn_mfma_f32_32x32x16_bf16(K1, qf1, st, 0, 0, 0); \
        st = __builtin_amdgcn_mfma_f32_32x32x16_bf16(K2, qf2, st, 0, 0, 0); \
        st = __builtin_amdgcn_mfma_f32_32x32x16_bf16(K3, qf3, st, 0, 0, 0); \
        __builtin_amdgcn_s_setprio(0);                                      \
        float m0_ = max3f(st[0], st[1], st[2]);                             \
        float m1_ = max3f(st[3], st[4], st[5]);                             \
        float m2_ = max3f(st[6], st[7], st[8]);                             \
        float m3_ = max3f(st[9], st[10], st[11]);                           \
        float m4_ = max3f(st[12], st[13], st[14]);                          \
        mex = max3f(mex, max3f(m0_, m1_, m2_), max3f(m3_, m4_, st[15]));    \
        unsigned pk0, pk1, pk2, pk3, pk4, pk5, pk6, pk7;                    \
        float rs_;                                                          \
        {                                                                   \
            float a_, b_;                                                   \
            a_ = __builtin_amdgcn_exp2f(st[0]);  b_ = __builtin_amdgcn_exp2f(st[1]);  \
            rs_ = a_ + b_;         pk0 = cvt_pk_bf16(a_, b_);               \
            a_ = __builtin_amdgcn_exp2f(st[2]);  b_ = __builtin_amdgcn_exp2f(st[3]);  \
            rs_ += a_ + b_;        pk1 = cvt_pk_bf16(a_, b_);               \
            a_ = __builtin_amdgcn_exp2f(st[4]);  b_ = __builtin_amdgcn_exp2f(st[5]);  \
            rs_ += a_ + b_;        pk2 = cvt_pk_bf16(a_, b_);               \
            a_ = __builtin_amdgcn_exp2f(st[6]);  b_ = __builtin_amdgcn_exp2f(st[7]);  \
            rs_ += a_ + b_;        pk3 = cvt_pk_bf16(a_, b_);               \
            a_ = __builtin_amdgcn_exp2f(st[8]);  b_ = __builtin_amdgcn_exp2f(st[9]);  \
            rs_ += a_ + b_;        pk4 = cvt_pk_bf16(a_, b_);               \
            a_ = __builtin_amdgcn_exp2f(st[10]); b_ = __builtin_amdgcn_exp2f(st[11]); \
            rs_ += a_ + b_;        pk5 = cvt_pk_bf16(a_, b_);               \
            a_ = __builtin_amdgcn_exp2f(st[12]); b_ = __builtin_amdgcn_exp2f(st[13]); \
            rs_ += a_ + b_;        pk6 = cvt_pk_bf16(a_, b_);               \
            a_ = __builtin_amdgcn_exp2f(st[14]); b_ = __builtin_amdgcn_exp2f(st[15]); \
            rs_ += a_ + b_;        pk7 = cvt_pk_bf16(a_, b_);               \
        }                                                                   \
        lsum += rs_;                                                        \
        ui4 va_ = { pk0, pk1, pk2, pk3 };                                   \
        ui4 vb_ = { pk4, pk5, pk6, pk7 };                                   \
        short8 pb0 = __builtin_bit_cast(short8, va_);                       \
        short8 pb1 = __builtin_bit_cast(short8, vb_);                       \
        __builtin_amdgcn_s_setprio(1);                                      \
        acc0 = __builtin_amdgcn_mfma_f32_32x32x16_bf16(vf0, pb0, acc0, 0, 0, 0); \
        acc0 = __builtin_amdgcn_mfma_f32_32x32x16_bf16(vf1, pb1, acc0, 0, 0, 0); \
        acc1 = __builtin_amdgcn_mfma_f32_32x32x16_bf16(vf2, pb0, acc1, 0, 0, 0); \
        acc1 = __builtin_amdgcn_mfma_f32_32x32x16_bf16(vf3, pb1, acc1, 0, 0, 0); \
        __builtin_amdgcn_s_setprio(0);                                      \
    } while (0)

#pragma unroll 1
    for (int rep = 0; rep < REP; ++rep) {
        const short* kp = kp0;
        const short* vp = vp0;
        LOADK(kA0, kA1, kA2, kA3);
#pragma unroll 1
        for (int T = 0; T < nt; T += 2) {
            LOADV();                                    // V for tile T
            LOADK(kB0, kB1, kB2, kB3);                  // K one tile ahead
            TILE(kA0, kA1, kA2, kA3);
            LOADV();                                    // V for tile T+1
            if (T + 2 < nt) LOADK(kA0, kA1, kA2, kA3);
            TILE(kB0, kB1, kB2, kB3);
        }
    }
#undef LOADK
#undef LOADV
#undef TILE

    // cross-half reductions; undo the REP x accumulation
    mex = fmaxf(mex, __shfl_xor(mex, 32));
    lsum += __shfl_xor(lsum, 32);
    const float invR = 1.0f / (float)REP;
    lsum *= invR;

    // write O^T partials (bf16): OTb[s*64+d][qrow]
#pragma unroll
    for (int r = 0; r < 16; ++r) {
        int d0 = (r & 3) + 8 * (r >> 2) + 4 * hi;
        OTb[(size_t)(s * 64 + d0) * N + qrow]      = f32_to_bf16_bits(acc0[r] * invR);
        OTb[(size_t)(s * 64 + 32 + d0) * N + qrow] = f32_to_bf16_bits(acc1[r] * invR);
    }
    if (hi == 0) {
        Ml[(size_t)(s * 2 + 0) * N + qrow] = lsum;
        Ml[(size_t)(s * 2 + 1) * N + qrow] = mex;
    }
}

// ---- combine v2: 4x blocks, 1/4 per-thread work (TLP fix) ----
// grid = (N/64)*4; block b: rows [ (b>>2)*64, +64 ), dims [ (b&3)*16, +16 )
__global__ __launch_bounds__(256) void fa_comb_kernel(const short* __restrict__ OTb,
                                                      const float* __restrict__ Ml,
                                                      float* __restrict__ Out, int S) {
    const int qb = blockIdx.x >> 2, db4 = blockIdx.x & 3;
    const int row = threadIdx.x & 63, dd = threadIdx.x >> 6;
    const int grow = qb * 64 + row;
    const int d0 = db4 * 16 + dd * 4;

    float v0 = 0.f, v1 = 0.f, v2 = 0.f, v3 = 0.f;
    float L = 0.f, mg = -INFINITY;
    for (int s = 0; s < S; ++s) {
        size_t base = (size_t)(s * 64 + d0) * N + grow;
        v0 += bfbits_to_f32((unsigned short)OTb[base]);
        v1 += bfbits_to_f32((unsigned short)OTb[base + (size_t)N]);
        v2 += bfbits_to_f32((unsigned short)OTb[base + (size_t)2 * N]);
        v3 += bfbits_to_f32((unsigned short)OTb[base + (size_t)3 * N]);
        L  += Ml[(size_t)(s * 2 + 0) * N + grow];
        mg = fmaxf(mg, Ml[(size_t)(s * 2 + 1) * N + grow]);
    }
    float inv = 1.0f / L;
    float4 o = { v0 * inv, v1 * inv, v2 * inv, v3 * inv };
    *(float4*)(Out + (size_t)grow * D + d0) = o;
    if (db4 == 0 && dd == 0) Out[(size_t)N * D + grow] = exp2f(-mg) * L;
}

extern "C" void kernel_launch(void* const* d_in, const int* in_sizes, int n_in,
                              void* d_out, int out_size, void* d_ws, size_t ws_size,
                              hipStream_t stream) {
    const float* q = (const float*)d_in[0];
    const float* k = (const float*)d_in[1];
    const float* v = (const float*)d_in[2];
    float* out = (float*)d_out;

    short* Qb = (short*)d_ws;                         // 1 MB
    short* Kp = Qb + (size_t)N * D;                   // 1 MB
    short* Vp = Kp + (size_t)N * D;                   // 1 MB
    short* OTb = (short*)((char*)d_ws + 3 * 1048576); // S*64*N bf16

    int S = 16;
    while (S > 1 &&
           3ull * 1048576 + (size_t)S * (64ull * N * 2) + (size_t)S * (2ull * N * 4) > ws_size)
        S >>= 1;
    float* Ml = (float*)(OTb + (size_t)S * 64 * N);
    int KN = N / S;

    fa_conv<<<1024, 256, 0, stream>>>(q, k, v, Qb, Kp, Vp);
    fa_part_kernel<<<64 * S, 256, 0, stream>>>(Qb, Kp, Vp, OTb, Ml, KN);
    fa_comb_kernel<<<(N / 64) * 4, 256, 0, stream>>>(OTb, Ml, out, S);
}

// Round 14
// 45.931 us; speedup vs baseline: 1.8001x; 1.8001x over previous
//
#include <hip/hip_runtime.h>
#include <hip/hip_bf16.h>
#include <math.h>

#define N 8192
#define D 64
// fold (1/sqrt(D)) * log2(e) into Q so S2 = Qs·K is in base-2 units
#define QSCALE 0.18033688011112042f

typedef __attribute__((ext_vector_type(8))) short short8;
typedef __attribute__((ext_vector_type(16))) float f32x16;
typedef __attribute__((ext_vector_type(4))) unsigned int ui4;

__device__ inline short f32_to_bf16_bits(float x) {
    unsigned u = __builtin_bit_cast(unsigned, x);
    u += 0x7FFFu + ((u >> 16) & 1u);   // RNE
    return (short)(u >> 16);
}
__device__ inline float bfbits_to_f32(unsigned short u) {
    return __builtin_bit_cast(float, ((unsigned)u) << 16);
}
// v_cvt_pk_bf16_f32: packs two f32 -> two bf16 (RNE) in one VALU op.
__device__ inline unsigned cvt_pk_bf16(float a, float b) {
    unsigned r;
    asm("v_cvt_pk_bf16_f32 %0, %1, %2" : "=v"(r) : "v"(a), "v"(b));
    return r;
}
__device__ inline float max3f(float a, float b, float c) {
    float d;
    asm("v_max3_f32 %0, %1, %2, %3" : "=v"(d) : "v"(a), "v"(b), "v"(c));
    return d;
}

// ---- fused prepass (identical to r12) ----
__global__ __launch_bounds__(256) void fa_conv(const float* __restrict__ q,
                                               const float* __restrict__ k,
                                               const float* __restrict__ v,
                                               short* __restrict__ Qb,
                                               short* __restrict__ Kp,
                                               short* __restrict__ Vp) {
    int bid = blockIdx.x, tid = threadIdx.x;
    if (bid < 512) {
        int i = (bid * 256 + tid) * 4;
        float4 a = *(const float4*)(q + i);
        unsigned lo = cvt_pk_bf16(a.x * QSCALE, a.y * QSCALE);
        unsigned hi = cvt_pk_bf16(a.z * QSCALE, a.w * QSCALE);
        unsigned long long u = (unsigned long long)lo | ((unsigned long long)hi << 32);
        *(unsigned long long*)(Qb + i) = u;
    } else if (bid < 768) {
        int t = bid - 512;
        int c = tid >> 6, l = tid & 63, ql = l & 31, hi = l >> 5;
        const float* src = k + (size_t)(t * 32 + ql) * D + c * 16 + hi * 8;
        float4 a = *(const float4*)(src);
        float4 b = *(const float4*)(src + 4);
        uint4 u = { cvt_pk_bf16(a.x, a.y), cvt_pk_bf16(a.z, a.w),
                    cvt_pk_bf16(b.x, b.y), cvt_pk_bf16(b.z, b.w) };
        *(uint4*)(Kp + (size_t)t * 2048 + c * 512 + l * 8) = u;
    } else {
        int t = bid - 768;
        int dt = tid >> 7, h = (tid >> 6) & 1, hi = (tid >> 5) & 1, ql = tid & 31;
        // kappa-reordered: slot j holds V[key t*32 + h*16 + 4*hi + (j&3) + 8*(j>>2)]
        const float* src = v + (size_t)(t * 32 + h * 16 + hi * 4) * D + dt * 32 + ql;
        float f[8];
#pragma unroll
        for (int j = 0; j < 8; ++j)
            f[j] = src[(size_t)((j & 3) + 8 * (j >> 2)) * D];
        uint4 u = { cvt_pk_bf16(f[0], f[1]), cvt_pk_bf16(f[2], f[3]),
                    cvt_pk_bf16(f[4], f[5]), cvt_pk_bf16(f[6], f[7]) };
        *(uint4*)(Vp + (size_t)t * 2048 + dt * 1024 + h * 512 + hi * 256 + ql * 8) = u;
    }
}

// ---- main: 32x32 swapped-operand FA partials, VALU-lean tile ----
__global__ __launch_bounds__(256) void fa_part_kernel(const short* __restrict__ Qb,
                                                      const short* __restrict__ Kp,
                                                      const short* __restrict__ Vp,
                                                      short* __restrict__ OTb,
                                                      float* __restrict__ Ml,
                                                      int KN) {
    const int qt = blockIdx.x & 63;
    const int s  = blockIdx.x >> 6;
    const int w = threadIdx.x >> 6, lane = threadIdx.x & 63;
    const int ql = lane & 31, hi = lane >> 5;
    const int qrow = qt * 128 + w * 32 + ql;

    const short* qp = Qb + (size_t)qrow * D + hi * 8;
    short8 qf0 = *(const short8*)(qp);
    short8 qf1 = *(const short8*)(qp + 16);
    short8 qf2 = *(const short8*)(qp + 32);
    short8 qf3 = *(const short8*)(qp + 48);

    f32x16 acc0 = {}, acc1 = {}, accl = {};
    const f32x16 zro = {};                // loop-invariant zero C for QK^T
    float mex = -INFINITY;

    const int t0 = (s * KN) >> 5, nt = KN >> 5;   // 32-key tiles
    const short* kp = Kp + (size_t)t0 * 2048 + lane * 8;
    const short* vp = Vp + (size_t)t0 * 2048 + lane * 8;

    const short one = (short)0x3F80;   // bf16 1.0
    const short8 ones = { one, one, one, one, one, one, one, one };

    short8 kA0, kA1, kA2, kA3, kB0, kB1, kB2, kB3;
    short8 vf0, vf1, vf2, vf3;

#define LOADK(d0, d1, d2, d3) do {                                         \
        d0 = *(const short8*)(kp);                                         \
        d1 = *(const short8*)(kp + 512);                                   \
        d2 = *(const short8*)(kp + 1024);                                  \
        d3 = *(const short8*)(kp + 1536);                                  \
        kp += 2048;                                                        \
    } while (0)
#define LOADV() do {                                                       \
        vf0 = *(const short8*)(vp);                                        \
        vf1 = *(const short8*)(vp + 512);                                  \
        vf2 = *(const short8*)(vp + 1024);                                 \
        vf3 = *(const short8*)(vp + 1536);                                 \
        vp += 2048;                                                        \
    } while (0)

    // One 32-key tile: QK^T(C=zro) -> max3 tree -> exp2+pack -> PV + ones-MFMA
#define TILE(K0, K1, K2, K3) do {                                           \
        __builtin_amdgcn_s_setprio(1);                                      \
        f32x16 st;                                                          \
        st = __builtin_amdgcn_mfma_f32_32x32x16_bf16(K0, qf0, zro, 0, 0, 0); \
        st = __builtin_amdgcn_mfma_f32_32x32x16_bf16(K1, qf1, st, 0, 0, 0); \
        st = __builtin_amdgcn_mfma_f32_32x32x16_bf16(K2, qf2, st, 0, 0, 0); \
        st = __builtin_amdgcn_mfma_f32_32x32x16_bf16(K3, qf3, st, 0, 0, 0); \
        __builtin_amdgcn_s_setprio(0);                                      \
        float m0_ = max3f(st[0], st[1], st[2]);                             \
        float m1_ = max3f(st[3], st[4], st[5]);                             \
        float m2_ = max3f(st[6], st[7], st[8]);                             \
        float m3_ = max3f(st[9], st[10], st[11]);                           \
        float m4_ = max3f(st[12], st[13], st[14]);                          \
        mex = max3f(mex, max3f(m0_, m1_, m2_), max3f(m3_, m4_, st[15]));    \
        unsigned pk0 = cvt_pk_bf16(__builtin_amdgcn_exp2f(st[0]),  __builtin_amdgcn_exp2f(st[1]));  \
        unsigned pk1 = cvt_pk_bf16(__builtin_amdgcn_exp2f(st[2]),  __builtin_amdgcn_exp2f(st[3]));  \
        unsigned pk2 = cvt_pk_bf16(__builtin_amdgcn_exp2f(st[4]),  __builtin_amdgcn_exp2f(st[5]));  \
        unsigned pk3 = cvt_pk_bf16(__builtin_amdgcn_exp2f(st[6]),  __builtin_amdgcn_exp2f(st[7]));  \
        unsigned pk4 = cvt_pk_bf16(__builtin_amdgcn_exp2f(st[8]),  __builtin_amdgcn_exp2f(st[9]));  \
        unsigned pk5 = cvt_pk_bf16(__builtin_amdgcn_exp2f(st[10]), __builtin_amdgcn_exp2f(st[11])); \
        unsigned pk6 = cvt_pk_bf16(__builtin_amdgcn_exp2f(st[12]), __builtin_amdgcn_exp2f(st[13])); \
        unsigned pk7 = cvt_pk_bf16(__builtin_amdgcn_exp2f(st[14]), __builtin_amdgcn_exp2f(st[15])); \
        ui4 va_ = { pk0, pk1, pk2, pk3 };                                   \
        ui4 vb_ = { pk4, pk5, pk6, pk7 };                                   \
        short8 pb0 = __builtin_bit_cast(short8, va_);                       \
        short8 pb1 = __builtin_bit_cast(short8, vb_);                       \
        __builtin_amdgcn_s_setprio(1);                                      \
        acc0 = __builtin_amdgcn_mfma_f32_32x32x16_bf16(vf0, pb0, acc0, 0, 0, 0); \
        acc0 = __builtin_amdgcn_mfma_f32_32x32x16_bf16(vf1, pb1, acc0, 0, 0, 0); \
        acc1 = __builtin_amdgcn_mfma_f32_32x32x16_bf16(vf2, pb0, acc1, 0, 0, 0); \
        acc1 = __builtin_amdgcn_mfma_f32_32x32x16_bf16(vf3, pb1, acc1, 0, 0, 0); \
        accl = __builtin_amdgcn_mfma_f32_32x32x16_bf16(ones, pb0, accl, 0, 0, 0); \
        accl = __builtin_amdgcn_mfma_f32_32x32x16_bf16(ones, pb1, accl, 0, 0, 0); \
        __builtin_amdgcn_s_setprio(0);                                      \
    } while (0)

    LOADK(kA0, kA1, kA2, kA3);
#pragma unroll 1
    for (int T = 0; T < nt; T += 2) {
        LOADV();                                    // V for tile T
        LOADK(kB0, kB1, kB2, kB3);                  // K one tile ahead
        TILE(kA0, kA1, kA2, kA3);
        LOADV();                                    // V for tile T+1
        if (T + 2 < nt) LOADK(kA0, kA1, kA2, kA3);
        TILE(kB0, kB1, kB2, kB3);
    }
#undef LOADK
#undef LOADV
#undef TILE

    // ones-MFMA row: accl[0] = full 32-key-per-tile rowsum accumulated (both halves)
    float lsum = accl[0];
    mex = fmaxf(mex, __shfl_xor(mex, 32));

    // write O^T partials (bf16): OTb[s*64+d][qrow]
#pragma unroll
    for (int r = 0; r < 16; ++r) {
        int d0 = (r & 3) + 8 * (r >> 2) + 4 * hi;
        OTb[(size_t)(s * 64 + d0) * N + qrow]      = f32_to_bf16_bits(acc0[r]);
        OTb[(size_t)(s * 64 + 32 + d0) * N + qrow] = f32_to_bf16_bits(acc1[r]);
    }
    if (hi == 0) {
        Ml[(size_t)(s * 2 + 0) * N + qrow] = lsum;
        Ml[(size_t)(s * 2 + 1) * N + qrow] = mex;
    }
}

// ---- combine v2: 4x blocks, 1/4 per-thread work ----
__global__ __launch_bounds__(256) void fa_comb_kernel(const short* __restrict__ OTb,
                                                      const float* __restrict__ Ml,
                                                      float* __restrict__ Out, int S) {
    const int qb = blockIdx.x >> 2, db4 = blockIdx.x & 3;
    const int row = threadIdx.x & 63, dd = threadIdx.x >> 6;
    const int grow = qb * 64 + row;
    const int d0 = db4 * 16 + dd * 4;

    float v0 = 0.f, v1 = 0.f, v2 = 0.f, v3 = 0.f;
    float L = 0.f, mg = -INFINITY;
    for (int s = 0; s < S; ++s) {
        size_t base = (size_t)(s * 64 + d0) * N + grow;
        v0 += bfbits_to_f32((unsigned short)OTb[base]);
        v1 += bfbits_to_f32((unsigned short)OTb[base + (size_t)N]);
        v2 += bfbits_to_f32((unsigned short)OTb[base + (size_t)2 * N]);
        v3 += bfbits_to_f32((unsigned short)OTb[base + (size_t)3 * N]);
        L  += Ml[(size_t)(s * 2 + 0) * N + grow];
        mg = fmaxf(mg, Ml[(size_t)(s * 2 + 1) * N + grow]);
    }
    float inv = 1.0f / L;
    float4 o = { v0 * inv, v1 * inv, v2 * inv, v3 * inv };
    *(float4*)(Out + (size_t)grow * D + d0) = o;
    if (db4 == 0 && dd == 0) Out[(size_t)N * D + grow] = exp2f(-mg) * L;
}

extern "C" void kernel_launch(void* const* d_in, const int* in_sizes, int n_in,
                              void* d_out, int out_size, void* d_ws, size_t ws_size,
                              hipStream_t stream) {
    const float* q = (const float*)d_in[0];
    const float* k = (const float*)d_in[1];
    const float* v = (const float*)d_in[2];
    float* out = (float*)d_out;

    short* Qb = (short*)d_ws;                         // 1 MB
    short* Kp = Qb + (size_t)N * D;                   // 1 MB
    short* Vp = Kp + (size_t)N * D;                   // 1 MB
    short* OTb = (short*)((char*)d_ws + 3 * 1048576); // S*64*N bf16

    int S = 16;
    while (S > 1 &&
           3ull * 1048576 + (size_t)S * (64ull * N * 2) + (size_t)S * (2ull * N * 4) > ws_size)
        S >>= 1;
    float* Ml = (float*)(OTb + (size_t)S * 64 * N);
    int KN = N / S;

    fa_conv<<<1024, 256, 0, stream>>>(q, k, v, Qb, Kp, Vp);
    fa_part_kernel<<<64 * S, 256, 0, stream>>>(Qb, Kp, Vp, OTb, Ml, KN);
    fa_comb_kernel<<<(N / 64) * 4, 256, 0, stream>>>(OTb, Ml, out, S);
}

// Round 15
// 45.300 us; speedup vs baseline: 1.8252x; 1.0139x over previous
//
#include <hip/hip_runtime.h>
#include <hip/hip_bf16.h>
#include <math.h>

#define N 8192
#define D 64
// fold (1/sqrt(D)) * log2(e) into Q so S2 = Qs·K is in base-2 units
#define QSCALE 0.18033688011112042f

typedef __attribute__((ext_vector_type(8))) short short8;
typedef __attribute__((ext_vector_type(16))) float f32x16;
typedef __attribute__((ext_vector_type(4))) unsigned int ui4;

__device__ inline short f32_to_bf16_bits(float x) {
    unsigned u = __builtin_bit_cast(unsigned, x);
    u += 0x7FFFu + ((u >> 16) & 1u);   // RNE
    return (short)(u >> 16);
}
__device__ inline float bfbits_to_f32(unsigned short u) {
    return __builtin_bit_cast(float, ((unsigned)u) << 16);
}
// v_cvt_pk_bf16_f32: packs two f32 -> two bf16 (RNE) in one VALU op.
__device__ inline unsigned cvt_pk_bf16(float a, float b) {
    unsigned r;
    asm("v_cvt_pk_bf16_f32 %0, %1, %2" : "=v"(r) : "v"(a), "v"(b));
    return r;
}
__device__ inline float max3f(float a, float b, float c) {
    float d;
    asm("v_max3_f32 %0, %1, %2, %3" : "=v"(d) : "v"(a), "v"(b), "v"(c));
    return d;
}

// ---- fused prepass (identical to r12) ----
__global__ __launch_bounds__(256) void fa_conv(const float* __restrict__ q,
                                               const float* __restrict__ k,
                                               const float* __restrict__ v,
                                               short* __restrict__ Qb,
                                               short* __restrict__ Kp,
                                               short* __restrict__ Vp) {
    int bid = blockIdx.x, tid = threadIdx.x;
    if (bid < 512) {
        int i = (bid * 256 + tid) * 4;
        float4 a = *(const float4*)(q + i);
        unsigned lo = cvt_pk_bf16(a.x * QSCALE, a.y * QSCALE);
        unsigned hi = cvt_pk_bf16(a.z * QSCALE, a.w * QSCALE);
        unsigned long long u = (unsigned long long)lo | ((unsigned long long)hi << 32);
        *(unsigned long long*)(Qb + i) = u;
    } else if (bid < 768) {
        int t = bid - 512;
        int c = tid >> 6, l = tid & 63, ql = l & 31, hi = l >> 5;
        const float* src = k + (size_t)(t * 32 + ql) * D + c * 16 + hi * 8;
        float4 a = *(const float4*)(src);
        float4 b = *(const float4*)(src + 4);
        uint4 u = { cvt_pk_bf16(a.x, a.y), cvt_pk_bf16(a.z, a.w),
                    cvt_pk_bf16(b.x, b.y), cvt_pk_bf16(b.z, b.w) };
        *(uint4*)(Kp + (size_t)t * 2048 + c * 512 + l * 8) = u;
    } else {
        int t = bid - 768;
        int dt = tid >> 7, h = (tid >> 6) & 1, hi = (tid >> 5) & 1, ql = tid & 31;
        // kappa-reordered: slot j holds V[key t*32 + h*16 + 4*hi + (j&3) + 8*(j>>2)]
        const float* src = v + (size_t)(t * 32 + h * 16 + hi * 4) * D + dt * 32 + ql;
        float f[8];
#pragma unroll
        for (int j = 0; j < 8; ++j)
            f[j] = src[(size_t)((j & 3) + 8 * (j >> 2)) * D];
        uint4 u = { cvt_pk_bf16(f[0], f[1]), cvt_pk_bf16(f[2], f[3]),
                    cvt_pk_bf16(f[4], f[5]), cvt_pk_bf16(f[6], f[7]) };
        *(uint4*)(Vp + (size_t)t * 2048 + dt * 1024 + h * 512 + hi * 256 + ql * 8) = u;
    }
}

// ---- main: r12's measured-best TILE (24.3 us/pass), zero cross-lane path ----
__global__ __launch_bounds__(256) void fa_part_kernel(const short* __restrict__ Qb,
                                                      const short* __restrict__ Kp,
                                                      const short* __restrict__ Vp,
                                                      short* __restrict__ OTb,
                                                      float* __restrict__ Ml,
                                                      int KN) {
    const int qt = blockIdx.x & 63;
    const int s  = blockIdx.x >> 6;
    const int w = threadIdx.x >> 6, lane = threadIdx.x & 63;
    const int ql = lane & 31, hi = lane >> 5;
    const int qrow = qt * 128 + w * 32 + ql;

    const short* qp = Qb + (size_t)qrow * D + hi * 8;
    short8 qf0 = *(const short8*)(qp);
    short8 qf1 = *(const short8*)(qp + 16);
    short8 qf2 = *(const short8*)(qp + 32);
    short8 qf3 = *(const short8*)(qp + 48);

    f32x16 acc0 = {}, acc1 = {};
    float mex = -INFINITY, lsum = 0.f;

    const int t0 = (s * KN) >> 5, nt = KN >> 5;   // 32-key tiles
    const short* kp = Kp + (size_t)t0 * 2048 + lane * 8;
    const short* vp = Vp + (size_t)t0 * 2048 + lane * 8;

    short8 kA0, kA1, kA2, kA3, kB0, kB1, kB2, kB3;
    short8 vf0, vf1, vf2, vf3;

#define LOADK(d0, d1, d2, d3) do {                                         \
        d0 = *(const short8*)(kp);                                         \
        d1 = *(const short8*)(kp + 512);                                   \
        d2 = *(const short8*)(kp + 1024);                                  \
        d3 = *(const short8*)(kp + 1536);                                  \
        kp += 2048;                                                        \
    } while (0)
#define LOADV() do {                                                       \
        vf0 = *(const short8*)(vp);                                        \
        vf1 = *(const short8*)(vp + 512);                                  \
        vf2 = *(const short8*)(vp + 1024);                                 \
        vf3 = *(const short8*)(vp + 1536);                                 \
        vp += 2048;                                                        \
    } while (0)

    // One 32-key tile: QK^T -> max3 tree -> exp2+pack+rowsum -> PV (no shuffles)
#define TILE(K0, K1, K2, K3) do {                                           \
        __builtin_amdgcn_s_setprio(1);                                      \
        f32x16 st = {};                                                     \
        st = __builtin_amdgcn_mfma_f32_32x32x16_bf16(K0, qf0, st, 0, 0, 0); \
        st = __builtin_amdgcn_mfma_f32_32x32x16_bf16(K1, qf1, st, 0, 0, 0); \
        st = __builtin_amdgcn_mfma_f32_32x32x16_bf16(K2, qf2, st, 0, 0, 0); \
        st = __builtin_amdgcn_mfma_f32_32x32x16_bf16(K3, qf3, st, 0, 0, 0); \
        __builtin_amdgcn_s_setprio(0);                                      \
        float m0_ = max3f(st[0], st[1], st[2]);                             \
        float m1_ = max3f(st[3], st[4], st[5]);                             \
        float m2_ = max3f(st[6], st[7], st[8]);                             \
        float m3_ = max3f(st[9], st[10], st[11]);                           \
        float m4_ = max3f(st[12], st[13], st[14]);                          \
        mex = max3f(mex, max3f(m0_, m1_, m2_), max3f(m3_, m4_, st[15]));    \
        unsigned pk0, pk1, pk2, pk3, pk4, pk5, pk6, pk7;                    \
        float rs_;                                                          \
        {                                                                   \
            float a_, b_;                                                   \
            a_ = __builtin_amdgcn_exp2f(st[0]);  b_ = __builtin_amdgcn_exp2f(st[1]);  \
            rs_ = a_ + b_;         pk0 = cvt_pk_bf16(a_, b_);               \
            a_ = __builtin_amdgcn_exp2f(st[2]);  b_ = __builtin_amdgcn_exp2f(st[3]);  \
            rs_ += a_ + b_;        pk1 = cvt_pk_bf16(a_, b_);               \
            a_ = __builtin_amdgcn_exp2f(st[4]);  b_ = __builtin_amdgcn_exp2f(st[5]);  \
            rs_ += a_ + b_;        pk2 = cvt_pk_bf16(a_, b_);               \
            a_ = __builtin_amdgcn_exp2f(st[6]);  b_ = __builtin_amdgcn_exp2f(st[7]);  \
            rs_ += a_ + b_;        pk3 = cvt_pk_bf16(a_, b_);               \
            a_ = __builtin_amdgcn_exp2f(st[8]);  b_ = __builtin_amdgcn_exp2f(st[9]);  \
            rs_ += a_ + b_;        pk4 = cvt_pk_bf16(a_, b_);               \
            a_ = __builtin_amdgcn_exp2f(st[10]); b_ = __builtin_amdgcn_exp2f(st[11]); \
            rs_ += a_ + b_;        pk5 = cvt_pk_bf16(a_, b_);               \
            a_ = __builtin_amdgcn_exp2f(st[12]); b_ = __builtin_amdgcn_exp2f(st[13]); \
            rs_ += a_ + b_;        pk6 = cvt_pk_bf16(a_, b_);               \
            a_ = __builtin_amdgcn_exp2f(st[14]); b_ = __builtin_amdgcn_exp2f(st[15]); \
            rs_ += a_ + b_;        pk7 = cvt_pk_bf16(a_, b_);               \
        }                                                                   \
        lsum += rs_;                                                        \
        ui4 va_ = { pk0, pk1, pk2, pk3 };                                   \
        ui4 vb_ = { pk4, pk5, pk6, pk7 };                                   \
        short8 pb0 = __builtin_bit_cast(short8, va_);                       \
        short8 pb1 = __builtin_bit_cast(short8, vb_);                       \
        __builtin_amdgcn_s_setprio(1);                                      \
        acc0 = __builtin_amdgcn_mfma_f32_32x32x16_bf16(vf0, pb0, acc0, 0, 0, 0); \
        acc0 = __builtin_amdgcn_mfma_f32_32x32x16_bf16(vf1, pb1, acc0, 0, 0, 0); \
        acc1 = __builtin_amdgcn_mfma_f32_32x32x16_bf16(vf2, pb0, acc1, 0, 0, 0); \
        acc1 = __builtin_amdgcn_mfma_f32_32x32x16_bf16(vf3, pb1, acc1, 0, 0, 0); \
        __builtin_amdgcn_s_setprio(0);                                      \
    } while (0)

    LOADK(kA0, kA1, kA2, kA3);
#pragma unroll 1
    for (int T = 0; T < nt; T += 2) {
        LOADV();                                    // V for tile T
        LOADK(kB0, kB1, kB2, kB3);                  // K one tile ahead
        TILE(kA0, kA1, kA2, kA3);
        LOADV();                                    // V for tile T+1
        if (T + 2 < nt) LOADK(kA0, kA1, kA2, kA3);
        TILE(kB0, kB1, kB2, kB3);
    }
#undef LOADK
#undef LOADV
#undef TILE

    // cross-half reductions (lane's 16 k-rows + partner's 16 = full 32 per q)
    mex = fmaxf(mex, __shfl_xor(mex, 32));
    lsum += __shfl_xor(lsum, 32);

    // write O^T partials (bf16): OTb[s*64+d][qrow]
#pragma unroll
    for (int r = 0; r < 16; ++r) {
        int d0 = (r & 3) + 8 * (r >> 2) + 4 * hi;
        OTb[(size_t)(s * 64 + d0) * N + qrow]      = f32_to_bf16_bits(acc0[r]);
        OTb[(size_t)(s * 64 + 32 + d0) * N + qrow] = f32_to_bf16_bits(acc1[r]);
    }
    if (hi == 0) {
        Ml[(size_t)(s * 2 + 0) * N + qrow] = lsum;
        Ml[(size_t)(s * 2 + 1) * N + qrow] = mex;
    }
}

// ---- combine v2: 4x blocks, 1/4 per-thread work ----
__global__ __launch_bounds__(256) void fa_comb_kernel(const short* __restrict__ OTb,
                                                      const float* __restrict__ Ml,
                                                      float* __restrict__ Out, int S) {
    const int qb = blockIdx.x >> 2, db4 = blockIdx.x & 3;
    const int row = threadIdx.x & 63, dd = threadIdx.x >> 6;
    const int grow = qb * 64 + row;
    const int d0 = db4 * 16 + dd * 4;

    float v0 = 0.f, v1 = 0.f, v2 = 0.f, v3 = 0.f;
    float L = 0.f, mg = -INFINITY;
    for (int s = 0; s < S; ++s) {
        size_t base = (size_t)(s * 64 + d0) * N + grow;
        v0 += bfbits_to_f32((unsigned short)OTb[base]);
        v1 += bfbits_to_f32((unsigned short)OTb[base + (size_t)N]);
        v2 += bfbits_to_f32((unsigned short)OTb[base + (size_t)2 * N]);
        v3 += bfbits_to_f32((unsigned short)OTb[base + (size_t)3 * N]);
        L  += Ml[(size_t)(s * 2 + 0) * N + grow];
        mg = fmaxf(mg, Ml[(size_t)(s * 2 + 1) * N + grow]);
    }
    float inv = 1.0f / L;
    float4 o = { v0 * inv, v1 * inv, v2 * inv, v3 * inv };
    *(float4*)(Out + (size_t)grow * D + d0) = o;
    if (db4 == 0 && dd == 0) Out[(size_t)N * D + grow] = exp2f(-mg) * L;
}

extern "C" void kernel_launch(void* const* d_in, const int* in_sizes, int n_in,
                              void* d_out, int out_size, void* d_ws, size_t ws_size,
                              hipStream_t stream) {
    const float* q = (const float*)d_in[0];
    const float* k = (const float*)d_in[1];
    const float* v = (const float*)d_in[2];
    float* out = (float*)d_out;

    short* Qb = (short*)d_ws;                         // 1 MB
    short* Kp = Qb + (size_t)N * D;                   // 1 MB
    short* Vp = Kp + (size_t)N * D;                   // 1 MB
    short* OTb = (short*)((char*)d_ws + 3 * 1048576); // S*64*N bf16

    int S = 16;
    while (S > 1 &&
           3ull * 1048576 + (size_t)S * (64ull * N * 2) + (size_t)S * (2ull * N * 4) > ws_size)
        S >>= 1;
    float* Ml = (float*)(OTb + (size_t)S * 64 * N);
    int KN = N / S;

    fa_conv<<<1024, 256, 0, stream>>>(q, k, v, Qb, Kp, Vp);
    fa_part_kernel<<<64 * S, 256, 0, stream>>>(Qb, Kp, Vp, OTb, Ml, KN);
    fa_comb_kernel<<<(N / 64) * 4, 256, 0, stream>>>(OTb, Ml, out, S);
}